// Round 21
// baseline (74.841 us; speedup 1.0000x reference)
//
#include <hip/hip_runtime.h>
#include <cstddef>
#include <cstdint>

// Problem constants: T=2048, B=8, C=1024, H=16, K=31, P=15
constexpr int T_ = 2048;
constexpr int B_ = 8;
constexpr int C_ = 1024;
constexpr int H_ = 16;
constexpr int K_ = 31;
constexpr int P_ = 15;
constexpr int M_ = T_ * B_;   // 16384
constexpr int N_ = H_ * K_;   // 496
constexpr int NP = 512;       // padded N, slot layout n' = h*32 + k

typedef _Float16 f16x4 __attribute__((ext_vector_type(4)));
typedef _Float16 f16x8 __attribute__((ext_vector_type(8)));
typedef float f32x4 __attribute__((ext_vector_type(4)));

__device__ __forceinline__ void async_cp16(const void* g, void* l) {
    __builtin_amdgcn_global_load_lds(
        (const __attribute__((address_space(1))) void*)g,
        (__attribute__((address_space(3))) void*)l, 16, 0, 0);
}

// ---------------------------------------------------------------------------
// K0: fused convert. X -> Xh fp16; W -> Wh (512x1024 fp16, slot layout
// n' = h*32+k; k==31 rows zero). Runs at ~85% HBM BW (floor). Unchanged.
// ---------------------------------------------------------------------------
constexpr int XCH = M_ * C_ / 8;    // 2,097,152 f16x8 chunks
constexpr int WCH = NP * C_ / 8;    // 65,536

__global__ __launch_bounds__(256)
void cvt_inputs(const float* __restrict__ X, const float* __restrict__ W,
                _Float16* __restrict__ Xh, _Float16* __restrict__ Wh) {
    const int id = blockIdx.x * 256 + threadIdx.x;
    if (id < XCH) {
        const float4 v0 = *(const float4*)(X + (size_t)id * 8);
        const float4 v1 = *(const float4*)(X + (size_t)id * 8 + 4);
        f16x8 hv;
        hv[0] = (_Float16)v0.x; hv[1] = (_Float16)v0.y;
        hv[2] = (_Float16)v0.z; hv[3] = (_Float16)v0.w;
        hv[4] = (_Float16)v1.x; hv[5] = (_Float16)v1.y;
        hv[6] = (_Float16)v1.z; hv[7] = (_Float16)v1.w;
        *(f16x8*)(Xh + (size_t)id * 8) = hv;
    } else {
        const int j = id - XCH;
        const int n = j >> 7, sp = j & 127;
        const int h = n >> 5, k = n & 31;
        f16x8 hv = {};
        if (k < 31) {
            const float* wp = W + (size_t)(h * 31 + k) * C_ + sp * 8;
            const float4 v0 = *(const float4*)(wp);
            const float4 v1 = *(const float4*)(wp + 4);
            hv[0] = (_Float16)v0.x; hv[1] = (_Float16)v0.y;
            hv[2] = (_Float16)v0.z; hv[3] = (_Float16)v0.w;
            hv[4] = (_Float16)v1.x; hv[5] = (_Float16)v1.y;
            hv[6] = (_Float16)v1.z; hv[7] = (_Float16)v1.w;
        }
        *(f16x8*)(Wh + (size_t)n * C_ + sp * 8) = hv;
    }
}

// ---------------------------------------------------------------------------
// K1: GEMM -> raw f16 logits Lg (slot layout). Counted-vmcnt pipeline
// (A 3-deep, B 2-deep, BK=64, 80 KB LDS, 2 blocks/CU). Direct f16 logit
// stores. Byte-identical to round 16/20 (proven best).
// ---------------------------------------------------------------------------
__global__ __launch_bounds__(256)
void gemm_logits(const _Float16* __restrict__ Xh,
                 const _Float16* __restrict__ Wh,
                 _Float16* __restrict__ Lg) {
    __shared__ _Float16 As[3][128 * 64];   // 48 KB
    __shared__ _Float16 Bs[2][128 * 64];   // 32 KB

    const int tid = threadIdx.x;
    const int lane = tid & 63;
    const int w = tid >> 6;
    const int wm = (w >> 1) * 64;
    const int wn = (w & 1) * 64;
    const int col = lane & 15;
    const int g = lane >> 4;

    const int id = (int)blockIdx.x;
    const int bx = (id & 7) | ((id >> 5) << 3);
    const int by = (id >> 3) & 3;
    const int m0 = bx * 128;
    const int n0 = by * 128;

    const _Float16* asrc[4];
    const _Float16* bsrc[4];
#pragma unroll
    for (int p = 0; p < 4; ++p) {
        const int ci = p * 256 + tid;
        const int r = ci >> 3, cs = ci & 7;
        const int cl = cs ^ (r & 7);
        asrc[p] = Xh + (size_t)(m0 + r) * C_ + cl * 8;
        bsrc[p] = Wh + (size_t)(n0 + r) * C_ + cl * 8;
    }

    f32x4 acc[4][4] = {};

#pragma unroll
    for (int p = 0; p < 4; ++p) {
        const int ci = p * 256 + tid;
        async_cp16(asrc[p], &As[0][ci * 8]);
    }
#pragma unroll
    for (int p = 0; p < 4; ++p) {
        const int ci = p * 256 + tid;
        async_cp16(bsrc[p], &Bs[0][ci * 8]);
    }
#pragma unroll
    for (int p = 0; p < 4; ++p) {
        const int ci = p * 256 + tid;
        async_cp16(asrc[p] + 64, &As[1][ci * 8]);
    }
    asm volatile("s_waitcnt vmcnt(4)" ::: "memory");
    __builtin_amdgcn_s_barrier();
    __builtin_amdgcn_sched_barrier(0);

    for (int t = 0; t < 16; ++t) {
        const int ca = t % 3, cb = t & 1;
        if (t < 15) {
            const int k1 = (t + 1) * 64;
#pragma unroll
            for (int p = 0; p < 4; ++p) {
                const int ci = p * 256 + tid;
                async_cp16(bsrc[p] + k1, &Bs[cb ^ 1][ci * 8]);
            }
        }
        if (t < 14) {
            const int k2 = (t + 2) * 64;
            const int ca2 = (t + 2) % 3;
#pragma unroll
            for (int p = 0; p < 4; ++p) {
                const int ci = p * 256 + tid;
                async_cp16(asrc[p] + k2, &As[ca2][ci * 8]);
            }
        }

        f16x8 a[2][4], b[2][4];
#pragma unroll
        for (int kk = 0; kk < 2; ++kk) {
#pragma unroll
            for (int mf = 0; mf < 4; ++mf) {
                const int row = wm + mf * 16 + col;
                const int c = ((kk << 2) | g) ^ (row & 7);
                a[kk][mf] = *(const f16x8*)&As[ca][row * 64 + c * 8];
            }
#pragma unroll
            for (int nf = 0; nf < 4; ++nf) {
                const int row = wn + nf * 16 + col;
                const int c = ((kk << 2) | g) ^ (row & 7);
                b[kk][nf] = *(const f16x8*)&Bs[cb][row * 64 + c * 8];
            }
        }
#pragma unroll
        for (int kk = 0; kk < 2; ++kk)
#pragma unroll
            for (int nf = 0; nf < 4; ++nf)
#pragma unroll
                for (int mf = 0; mf < 4; ++mf)
                    acc[mf][nf] = __builtin_amdgcn_mfma_f32_16x16x32_f16(
                        a[kk][mf], b[kk][nf], acc[mf][nf], 0, 0, 0);

        if (t < 14) {
            asm volatile("s_waitcnt vmcnt(4)" ::: "memory");
        } else {
            asm volatile("s_waitcnt vmcnt(0)" ::: "memory");
        }
        __builtin_amdgcn_s_barrier();
        __builtin_amdgcn_sched_barrier(0);
    }

    // ---- epilogue: raw f16 logits straight to global (slot layout) ----
    const int rb = g * 4;
#pragma unroll
    for (int nf = 0; nf < 4; ++nf) {
        const int nl = wn + nf * 16 + col;
#pragma unroll
        for (int mf = 0; mf < 4; ++mf) {
            const int row = wm + mf * 16 + rb;
#pragma unroll
            for (int r = 0; r < 4; ++r)
                Lg[(size_t)(m0 + row + r) * NP + n0 + nl] =
                    (_Float16)acc[mf][nf][r];
        }
    }
}

// ---------------------------------------------------------------------------
// K2: softmax + depthwise dynamic conv. NEW: 128 threads, thread = (c-slot,
// 8 consecutive t). Conv-loop LDS reads cut ~47%: 2 waves x (38 xs-b128 +
// 32 wq-b128) vs 4 waves x (34+32). Weights read as f16x8 (4 loads per t),
// converted lazily per-k with compile-time indices. Same grid, same LDS.
// ---------------------------------------------------------------------------
__global__ __launch_bounds__(128)
void dconv(const _Float16* __restrict__ Xh, const _Float16* __restrict__ Lg,
           float* __restrict__ out) {
    __shared__ float xs[94][64];           // 24 KB
    __shared__ _Float16 ws16[64][40];      // 5 KB (row stride 80 B = 5x16 B)

    const int tid = threadIdx.x;           // 0..127
    const int t0 = blockIdx.x * 64;
    const int bh = (int)blockIdx.y;
    const int b = bh >> 4, h = bh & 15;

    // stage x window rows t0-15 .. t0+78: f16x8 loads -> 2 swizzled f32x4
    for (int task = tid; task < 94 * 8; task += 128) {
        const int r = task >> 3, hc = task & 7;
        const int tp = t0 + r - 15;
        f16x8 v = {};
        if (tp >= 0 && tp < T_)
            v = *(const f16x8*)(Xh + ((size_t)tp * B_ + b) * C_ + h * 64 + hc * 8);
        f32x4 lo, hi;
        lo[0] = (float)v[0]; lo[1] = (float)v[1];
        lo[2] = (float)v[2]; lo[3] = (float)v[3];
        hi[0] = (float)v[4]; hi[1] = (float)v[5];
        hi[2] = (float)v[6]; hi[3] = (float)v[7];
        const int c0 = (2 * hc) ^ (r & 7), c1 = (2 * hc + 1) ^ (r & 7);
        *(f32x4*)&xs[r][c0 * 4] = lo;
        *(f32x4*)&xs[r][c1 * 4] = hi;
    }
    // stage raw logits (two f16x8 per thread)
#pragma unroll
    for (int p = 0; p < 2; ++p) {
        const int q = tid + p * 128;       // 0..255
        const int t = q >> 2, kc = (q & 3) * 8;
        const f16x8 wv =
            *(const f16x8*)(Lg + ((size_t)(t0 + t) * B_ + b) * NP + h * 32 + kc);
        *(f16x8*)&ws16[t][kc] = wv;
    }
    __syncthreads();

    // in-LDS softmax: one row per thread, tid < 64
    if (tid < 64) {
        float v[31];
        float mx = -1e30f;
#pragma unroll
        for (int k = 0; k < 31; ++k) {
            v[k] = (float)ws16[tid][k];
            mx = fmaxf(mx, v[k]);
        }
        float ssum = 0.f;
#pragma unroll
        for (int k = 0; k < 31; ++k) { v[k] = __expf(v[k] - mx); ssum += v[k]; }
        const float inv = 1.f / ssum;
#pragma unroll
        for (int k = 0; k < 31; ++k) ws16[tid][k] = (_Float16)(v[k] * inv);
    }
    __syncthreads();

    const int s = tid & 15;                // channel slot (4 f32)
    const int tg8 = (tid >> 4) * 8;        // first of this thread's 8 t's
    f32x4 acc[8] = {};
    f16x8 wq[8];

#pragma unroll
    for (int rr = 0; rr < 38; ++rr) {
        const int r = tg8 + rr;
        const f32x4 xv = *(const f32x4*)&xs[r][(s ^ (r & 7)) * 4];
#pragma unroll
        for (int i = 0; i < 8; ++i) {
            const int k = rr - i;
            if (k < 0 || k > 30) continue;
            if ((k & 7) == 0) wq[i] = *(const f16x8*)&ws16[tg8 + i][k];
            acc[i] += (float)wq[i][k & 7] * xv;
        }
    }

#pragma unroll
    for (int i = 0; i < 8; ++i) {
        const int t = t0 + tg8 + i;
        *(f32x4*)(out + ((size_t)t * B_ + b) * C_ + h * 64 + s * 4) = acc[i];
    }
}

// ---------------------------------------------------------------------------
extern "C" void kernel_launch(void* const* d_in, const int* in_sizes, int n_in,
                              void* d_out, int out_size, void* d_ws,
                              size_t ws_size, hipStream_t stream) {
    const float* X = (const float*)d_in[0];
    const float* W = (const float*)d_in[1];
    float* out = (float*)d_out;

    // workspace: Wh (1 MiB) | Lg (16 MiB) | Xh (32 MiB)  = 49 MiB
    _Float16* Wh = (_Float16*)d_ws;
    _Float16* Lg = (_Float16*)((char*)d_ws + (size_t)NP * C_ * 2);
    _Float16* Xh = (_Float16*)((char*)d_ws + (size_t)NP * C_ * 2 +
                               (size_t)M_ * NP * 2);

    cvt_inputs<<<(XCH + WCH) / 256, 256, 0, stream>>>(X, W, Xh, Wh);
    gemm_logits<<<512, 256, 0, stream>>>(Xh, Wh, Lg);
    dconv<<<dim3(T_ / 64, B_ * H_), 128, 0, stream>>>(Xh, Lg, out);
}

// Round 22
// 70.377 us; speedup vs baseline: 1.0634x; 1.0634x over previous
//
#include <hip/hip_runtime.h>
#include <cstddef>
#include <cstdint>

// Problem constants: T=2048, B=8, C=1024, H=16, K=31, P=15
constexpr int T_ = 2048;
constexpr int B_ = 8;
constexpr int C_ = 1024;
constexpr int H_ = 16;
constexpr int K_ = 31;
constexpr int P_ = 15;
constexpr int M_ = T_ * B_;   // 16384
constexpr int N_ = H_ * K_;   // 496
constexpr int NP = 512;       // padded N, slot layout n' = h*32 + k

typedef _Float16 f16x4 __attribute__((ext_vector_type(4)));
typedef _Float16 f16x8 __attribute__((ext_vector_type(8)));
typedef float f32x4 __attribute__((ext_vector_type(4)));

__device__ __forceinline__ void async_cp16(const void* g, void* l) {
    __builtin_amdgcn_global_load_lds(
        (const __attribute__((address_space(1))) void*)g,
        (__attribute__((address_space(3))) void*)l, 16, 0, 0);
}

// ---------------------------------------------------------------------------
// K0: fused convert. X -> Xh fp16; W -> Wh (512x1024 fp16, slot layout
// n' = h*32+k; k==31 rows zero). Runs at ~85% HBM BW (floor).
// ---------------------------------------------------------------------------
constexpr int XCH = M_ * C_ / 8;    // 2,097,152 f16x8 chunks
constexpr int WCH = NP * C_ / 8;    // 65,536

__global__ __launch_bounds__(256)
void cvt_inputs(const float* __restrict__ X, const float* __restrict__ W,
                _Float16* __restrict__ Xh, _Float16* __restrict__ Wh) {
    const int id = blockIdx.x * 256 + threadIdx.x;
    if (id < XCH) {
        const float4 v0 = *(const float4*)(X + (size_t)id * 8);
        const float4 v1 = *(const float4*)(X + (size_t)id * 8 + 4);
        f16x8 hv;
        hv[0] = (_Float16)v0.x; hv[1] = (_Float16)v0.y;
        hv[2] = (_Float16)v0.z; hv[3] = (_Float16)v0.w;
        hv[4] = (_Float16)v1.x; hv[5] = (_Float16)v1.y;
        hv[6] = (_Float16)v1.z; hv[7] = (_Float16)v1.w;
        *(f16x8*)(Xh + (size_t)id * 8) = hv;
    } else {
        const int j = id - XCH;
        const int n = j >> 7, sp = j & 127;
        const int h = n >> 5, k = n & 31;
        f16x8 hv = {};
        if (k < 31) {
            const float* wp = W + (size_t)(h * 31 + k) * C_ + sp * 8;
            const float4 v0 = *(const float4*)(wp);
            const float4 v1 = *(const float4*)(wp + 4);
            hv[0] = (_Float16)v0.x; hv[1] = (_Float16)v0.y;
            hv[2] = (_Float16)v0.z; hv[3] = (_Float16)v0.w;
            hv[4] = (_Float16)v1.x; hv[5] = (_Float16)v1.y;
            hv[6] = (_Float16)v1.z; hv[7] = (_Float16)v1.w;
        }
        *(f16x8*)(Wh + (size_t)n * C_ + sp * 8) = hv;
    }
}

// ---------------------------------------------------------------------------
// K1: GEMM -> raw f16 logits Lg (slot layout). Counted-vmcnt pipeline
// (A 3-deep, B 2-deep, BK=64, 80 KB LDS, 2 blocks/CU). Epilogue: direct
// f16 stores of acc (no LDS overlay, no barriers — softmax lives in dconv).
// Proven best: rounds 16/20, 70.1-70.2 us total.
// ---------------------------------------------------------------------------
__global__ __launch_bounds__(256)
void gemm_logits(const _Float16* __restrict__ Xh,
                 const _Float16* __restrict__ Wh,
                 _Float16* __restrict__ Lg) {
    __shared__ _Float16 As[3][128 * 64];   // 48 KB
    __shared__ _Float16 Bs[2][128 * 64];   // 32 KB

    const int tid = threadIdx.x;
    const int lane = tid & 63;
    const int w = tid >> 6;
    const int wm = (w >> 1) * 64;
    const int wn = (w & 1) * 64;
    const int col = lane & 15;
    const int g = lane >> 4;

    const int id = (int)blockIdx.x;
    const int bx = (id & 7) | ((id >> 5) << 3);
    const int by = (id >> 3) & 3;
    const int m0 = bx * 128;
    const int n0 = by * 128;

    const _Float16* asrc[4];
    const _Float16* bsrc[4];
#pragma unroll
    for (int p = 0; p < 4; ++p) {
        const int ci = p * 256 + tid;
        const int r = ci >> 3, cs = ci & 7;
        const int cl = cs ^ (r & 7);
        asrc[p] = Xh + (size_t)(m0 + r) * C_ + cl * 8;
        bsrc[p] = Wh + (size_t)(n0 + r) * C_ + cl * 8;
    }

    f32x4 acc[4][4] = {};

#pragma unroll
    for (int p = 0; p < 4; ++p) {
        const int ci = p * 256 + tid;
        async_cp16(asrc[p], &As[0][ci * 8]);
    }
#pragma unroll
    for (int p = 0; p < 4; ++p) {
        const int ci = p * 256 + tid;
        async_cp16(bsrc[p], &Bs[0][ci * 8]);
    }
#pragma unroll
    for (int p = 0; p < 4; ++p) {
        const int ci = p * 256 + tid;
        async_cp16(asrc[p] + 64, &As[1][ci * 8]);
    }
    asm volatile("s_waitcnt vmcnt(4)" ::: "memory");
    __builtin_amdgcn_s_barrier();
    __builtin_amdgcn_sched_barrier(0);

    for (int t = 0; t < 16; ++t) {
        const int ca = t % 3, cb = t & 1;
        if (t < 15) {
            const int k1 = (t + 1) * 64;
#pragma unroll
            for (int p = 0; p < 4; ++p) {
                const int ci = p * 256 + tid;
                async_cp16(bsrc[p] + k1, &Bs[cb ^ 1][ci * 8]);
            }
        }
        if (t < 14) {
            const int k2 = (t + 2) * 64;
            const int ca2 = (t + 2) % 3;
#pragma unroll
            for (int p = 0; p < 4; ++p) {
                const int ci = p * 256 + tid;
                async_cp16(asrc[p] + k2, &As[ca2][ci * 8]);
            }
        }

        f16x8 a[2][4], b[2][4];
#pragma unroll
        for (int kk = 0; kk < 2; ++kk) {
#pragma unroll
            for (int mf = 0; mf < 4; ++mf) {
                const int row = wm + mf * 16 + col;
                const int c = ((kk << 2) | g) ^ (row & 7);
                a[kk][mf] = *(const f16x8*)&As[ca][row * 64 + c * 8];
            }
#pragma unroll
            for (int nf = 0; nf < 4; ++nf) {
                const int row = wn + nf * 16 + col;
                const int c = ((kk << 2) | g) ^ (row & 7);
                b[kk][nf] = *(const f16x8*)&Bs[cb][row * 64 + c * 8];
            }
        }
#pragma unroll
        for (int kk = 0; kk < 2; ++kk)
#pragma unroll
            for (int nf = 0; nf < 4; ++nf)
#pragma unroll
                for (int mf = 0; mf < 4; ++mf)
                    acc[mf][nf] = __builtin_amdgcn_mfma_f32_16x16x32_f16(
                        a[kk][mf], b[kk][nf], acc[mf][nf], 0, 0, 0);

        if (t < 14) {
            asm volatile("s_waitcnt vmcnt(4)" ::: "memory");
        } else {
            asm volatile("s_waitcnt vmcnt(0)" ::: "memory");
        }
        __builtin_amdgcn_s_barrier();
        __builtin_amdgcn_sched_barrier(0);
    }

    // ---- epilogue: raw f16 logits straight to global (slot layout) ----
    const int rb = g * 4;
#pragma unroll
    for (int nf = 0; nf < 4; ++nf) {
        const int nl = wn + nf * 16 + col;
#pragma unroll
        for (int mf = 0; mf < 4; ++mf) {
            const int row = wm + mf * 16 + rb;
#pragma unroll
            for (int r = 0; r < 4; ++r)
                Lg[(size_t)(m0 + row + r) * NP + n0 + nl] =
                    (_Float16)acc[mf][nf][r];
        }
    }
}

// ---------------------------------------------------------------------------
// K2: softmax + depthwise dynamic conv. Stages raw logits into ws16[64][40]
// f16, softmaxes in-place (1 wave, hidden under memory phase at high
// occupancy), conv weights converted f16->f32 at use. Round-16/20 proven.
// ---------------------------------------------------------------------------
__global__ __launch_bounds__(256)
void dconv(const _Float16* __restrict__ Xh, const _Float16* __restrict__ Lg,
           float* __restrict__ out) {
    __shared__ float xs[94][64];           // 24 KB
    __shared__ _Float16 ws16[64][40];      // 5 KB

    const int tid = threadIdx.x;
    const int t0 = blockIdx.x * 64;
    const int bh = (int)blockIdx.y;
    const int b = bh >> 4, h = bh & 15;

    // stage x window rows t0-15 .. t0+78: f16x8 loads -> 2 swizzled f32x4
    for (int task = tid; task < 94 * 8; task += 256) {
        const int r = task >> 3, hc = task & 7;
        const int tp = t0 + r - 15;
        f16x8 v = {};
        if (tp >= 0 && tp < T_)
            v = *(const f16x8*)(Xh + ((size_t)tp * B_ + b) * C_ + h * 64 + hc * 8);
        f32x4 lo, hi;
        lo[0] = (float)v[0]; lo[1] = (float)v[1];
        lo[2] = (float)v[2]; lo[3] = (float)v[3];
        hi[0] = (float)v[4]; hi[1] = (float)v[5];
        hi[2] = (float)v[6]; hi[3] = (float)v[7];
        const int c0 = (2 * hc) ^ (r & 7), c1 = (2 * hc + 1) ^ (r & 7);
        *(f32x4*)&xs[r][c0 * 4] = lo;
        *(f32x4*)&xs[r][c1 * 4] = hi;
    }
    // stage raw logits (f16 copy, one f16x8 per thread)
    {
        const int t = tid >> 2, kc = (tid & 3) * 8;
        const f16x8 wv =
            *(const f16x8*)(Lg + ((size_t)(t0 + t) * B_ + b) * NP + h * 32 + kc);
        *(f16x8*)&ws16[t][kc] = wv;
    }
    __syncthreads();

    // in-LDS softmax: one row per thread, tid < 64
    if (tid < 64) {
        float v[31];
        float mx = -1e30f;
#pragma unroll
        for (int k = 0; k < 31; ++k) {
            v[k] = (float)ws16[tid][k];
            mx = fmaxf(mx, v[k]);
        }
        float ssum = 0.f;
#pragma unroll
        for (int k = 0; k < 31; ++k) { v[k] = __expf(v[k] - mx); ssum += v[k]; }
        const float inv = 1.f / ssum;
#pragma unroll
        for (int k = 0; k < 31; ++k) ws16[tid][k] = (_Float16)(v[k] * inv);
    }
    __syncthreads();

    const int s = tid & 15;
    const int tg4 = (tid >> 4) * 4;
    f32x4 acc[4] = {};
    f32x4 wc[4];

#pragma unroll
    for (int rr = 0; rr < 34; ++rr) {
        const int r = tg4 + rr;
        const f32x4 xv = *(const f32x4*)&xs[r][(s ^ (r & 7)) * 4];
#pragma unroll
        for (int i = 0; i < 4; ++i) {
            const int k = rr - i;
            if (k < 0 || k > 30) continue;
            if ((k & 3) == 0) {
                const f16x4 wq = *(const f16x4*)&ws16[tg4 + i][k];
                wc[i][0] = (float)wq[0]; wc[i][1] = (float)wq[1];
                wc[i][2] = (float)wq[2]; wc[i][3] = (float)wq[3];
            }
            acc[i] += wc[i][k & 3] * xv;
        }
    }

#pragma unroll
    for (int i = 0; i < 4; ++i) {
        const int t = t0 + tg4 + i;
        *(f32x4*)(out + ((size_t)t * B_ + b) * C_ + h * 64 + s * 4) = acc[i];
    }
}

// ---------------------------------------------------------------------------
extern "C" void kernel_launch(void* const* d_in, const int* in_sizes, int n_in,
                              void* d_out, int out_size, void* d_ws,
                              size_t ws_size, hipStream_t stream) {
    const float* X = (const float*)d_in[0];
    const float* W = (const float*)d_in[1];
    float* out = (float*)d_out;

    // workspace: Wh (1 MiB) | Lg (16 MiB) | Xh (32 MiB)  = 49 MiB
    _Float16* Wh = (_Float16*)d_ws;
    _Float16* Lg = (_Float16*)((char*)d_ws + (size_t)NP * C_ * 2);
    _Float16* Xh = (_Float16*)((char*)d_ws + (size_t)NP * C_ * 2 +
                               (size_t)M_ * NP * 2);

    cvt_inputs<<<(XCH + WCH) / 256, 256, 0, stream>>>(X, W, Xh, Wh);
    gemm_logits<<<512, 256, 0, stream>>>(Xh, Wh, Lg);
    dconv<<<dim3(T_ / 64, B_ * H_), 256, 0, stream>>>(Xh, Lg, out);
}